// Round 6
// baseline (185.445 us; speedup 1.0000x reference)
//
#include <hip/hip_runtime.h>
#include <hip/hip_bf16.h>

// B=8, T=2048, D=1024, HS=128 causal attention head.
// wprep (W->Wt bf16) ; qkv_gemm (64x128 tile, BK=128, reg dbuf, V transposed)
// attn (fixed-base softmax, 4- or 8-way key split by ws_size, 8 waves) ; merge.

typedef __bf16 bf16x8 __attribute__((ext_vector_type(8)));
typedef __bf16 bf16x4 __attribute__((ext_vector_type(4)));
typedef float floatx4 __attribute__((ext_vector_type(4)));

#define B_  8
#define T_  2048
#define D_  1024
#define HS_ 128
#define M_  (B_ * T_)   // 16384

#define OFF_Q   0u
#define OFF_K   4194304u
#define OFF_VT  8388608u
#define OFF_WT  12582912u          // 3*128*1024*2 = 786432
#define OFF_OP  13369344u          // nsplit * 16384*128*2 (bf16) slots of 4 MB

// ---------------------------------------------------------------------------
// W[1024,128] fp32 -> Wt[128,1024] bf16 (x3), coalesced via LDS transpose.
// ---------------------------------------------------------------------------
__global__ __launch_bounds__(256) void wprep(
    const float* __restrict__ Wq, const float* __restrict__ Wk,
    const float* __restrict__ Wv, __hip_bfloat16* __restrict__ Wt)
{
    __shared__ __align__(16) __hip_bfloat16 sT[128][80];
    const int wsel = blockIdx.y;
    const int k0   = blockIdx.x * 64;
    const float* W = (wsel == 0) ? Wq : ((wsel == 1) ? Wk : Wv);

    #pragma unroll
    for (int i = 0; i < 8; ++i) {
        const int idx = threadIdx.x + i * 256;
        const int kr  = idx >> 5;
        const int f4  = idx & 31;
        const float4 v = *(const float4*)(W + (size_t)(k0 + kr) * HS_ + f4 * 4);
        sT[f4 * 4 + 0][kr] = __float2bfloat16(v.x);
        sT[f4 * 4 + 1][kr] = __float2bfloat16(v.y);
        sT[f4 * 4 + 2][kr] = __float2bfloat16(v.z);
        sT[f4 * 4 + 3][kr] = __float2bfloat16(v.w);
    }
    __syncthreads();
    #pragma unroll
    for (int i = 0; i < 4; ++i) {
        const int idx = threadIdx.x + i * 256;
        const int n   = idx >> 3;
        const int sg  = idx & 7;
        *(bf16x8*)(Wt + (size_t)wsel * HS_ * D_ + (size_t)n * D_ + k0 + sg * 8) =
            *(const bf16x8*)&sT[n][sg * 8];
    }
}

// ---------------------------------------------------------------------------
// QKV GEMM: C[16384,128] = bf16(x)*Wt^T. Tile 64x128, BK=128 (8 iters),
// grid (256,3)=768 blocks (3/CU). Padded LDS, register double-buffer.
// Waves 2x2: 32 rows x 64 cols each. V written transposed [b][hs][t].
// ---------------------------------------------------------------------------
__global__ __launch_bounds__(256, 3) void qkv_gemm(
    const float* __restrict__ x, const __hip_bfloat16* __restrict__ Wt_all,
    __hip_bfloat16* __restrict__ qg, __hip_bfloat16* __restrict__ kg,
    __hip_bfloat16* __restrict__ vtg)
{
    __shared__ __align__(16) __hip_bfloat16 sA[64][136];    // 272B stride: <=2-way
    __shared__ __align__(16) __hip_bfloat16 sB[128][136];

    const int mt   = blockIdx.x;
    const int wsel = blockIdx.y;
    const __hip_bfloat16* Wt = Wt_all + (size_t)wsel * HS_ * D_;

    const int tid  = threadIdx.x;
    const int lane = tid & 63;
    const int w    = tid >> 6;
    const int quad = lane >> 4;
    const int l16  = lane & 15;
    const int wrow = (w & 1) * 32;
    const int wcol = (w >> 1) * 64;
    const int m0   = mt * 64;

    const int srA = tid >> 2, scA = (tid & 3) * 32;   // A: 64 rows x 32 floats/thread
    const int srB = tid >> 1, scB = (tid & 1) * 64;   // B: 128 rows x 64 bf16/thread

    floatx4 acc[2][4];
    #pragma unroll
    for (int i = 0; i < 2; ++i)
        #pragma unroll
        for (int j = 0; j < 4; ++j) acc[i][j] = (floatx4){0.f, 0.f, 0.f, 0.f};

    float4 pa[8];
    bf16x8 pb[8];
    const float* arow = x + (size_t)(m0 + srA) * D_ + scA;
    const __hip_bfloat16* browp = Wt + (size_t)srB * D_ + scB;

    // preload K-tile 0
    #pragma unroll
    for (int jj = 0; jj < 8; ++jj) {
        pa[jj] = *(const float4*)(arow + jj * 4);
        pb[jj] = *(const bf16x8*)(browp + jj * 8);
    }

    for (int kt = 0; kt < D_ / 128; ++kt) {
        __syncthreads();   // prior tile's LDS reads complete
        #pragma unroll
        for (int jj = 0; jj < 4; ++jj) {
            union { bf16x8 v; __hip_bfloat16 h[8]; } u;
            u.h[0] = __float2bfloat16(pa[2 * jj].x);     u.h[1] = __float2bfloat16(pa[2 * jj].y);
            u.h[2] = __float2bfloat16(pa[2 * jj].z);     u.h[3] = __float2bfloat16(pa[2 * jj].w);
            u.h[4] = __float2bfloat16(pa[2 * jj + 1].x); u.h[5] = __float2bfloat16(pa[2 * jj + 1].y);
            u.h[6] = __float2bfloat16(pa[2 * jj + 1].z); u.h[7] = __float2bfloat16(pa[2 * jj + 1].w);
            *(bf16x8*)&sA[srA][scA + jj * 8] = u.v;
        }
        #pragma unroll
        for (int jj = 0; jj < 8; ++jj)
            *(bf16x8*)&sB[srB][scB + jj * 8] = pb[jj];

        if (kt + 1 < D_ / 128) {   // issue next tile's loads (regs now free)
            const float* an = arow + (kt + 1) * 128;
            const __hip_bfloat16* bn = browp + (kt + 1) * 128;
            #pragma unroll
            for (int jj = 0; jj < 8; ++jj) {
                pa[jj] = *(const float4*)(an + jj * 4);
                pb[jj] = *(const bf16x8*)(bn + jj * 8);
            }
        }
        __syncthreads();

        #pragma unroll
        for (int ks = 0; ks < 4; ++ks) {
            bf16x8 af[2], bfr[4];
            #pragma unroll
            for (int i = 0; i < 2; ++i)
                af[i] = *(const bf16x8*)&sA[wrow + i * 16 + l16][ks * 32 + quad * 8];
            #pragma unroll
            for (int j = 0; j < 4; ++j)
                bfr[j] = *(const bf16x8*)&sB[wcol + j * 16 + l16][ks * 32 + quad * 8];
            #pragma unroll
            for (int i = 0; i < 2; ++i)
                #pragma unroll
                for (int j = 0; j < 4; ++j)
                    acc[i][j] = __builtin_amdgcn_mfma_f32_16x16x32_bf16(af[i], bfr[j], acc[i][j], 0, 0, 0);
        }
    }

    if (wsel < 2) {
        __hip_bfloat16* out = wsel ? kg : qg;
        #pragma unroll
        for (int i = 0; i < 2; ++i)
            #pragma unroll
            for (int j = 0; j < 4; ++j)
                #pragma unroll
                for (int r = 0; r < 4; ++r)
                    out[(size_t)(m0 + wrow + i * 16 + quad * 4 + r) * HS_ + wcol + j * 16 + l16] =
                        __float2bfloat16(acc[i][j][r]);
    } else {
        #pragma unroll
        for (int i = 0; i < 2; ++i) {
            const int row0 = m0 + wrow + i * 16 + quad * 4;
            const int bb = row0 >> 11;
            const int t  = row0 & 2047;
            #pragma unroll
            for (int j = 0; j < 4; ++j) {
                const int col = wcol + j * 16 + l16;
                union { bf16x4 v; __hip_bfloat16 h[4]; } u;
                #pragma unroll
                for (int r = 0; r < 4; ++r) u.h[r] = __float2bfloat16(acc[i][j][r]);
                *(bf16x4*)(vtg + (size_t)bb * HS_ * T_ + (size_t)col * T_ + t) = u.v;
            }
        }
    }
}

// ---------------------------------------------------------------------------
// Flash attention, fixed-base softmax. grid (nsplit, 16, 8), 512 thr = 8 waves,
// 128 q-rows/block. Padded LDS, register prefetch. lg = log2(nsplit).
// ---------------------------------------------------------------------------
__global__ __launch_bounds__(512) void attn(
    const __hip_bfloat16* __restrict__ qg, const __hip_bfloat16* __restrict__ kg,
    const __hip_bfloat16* __restrict__ vtg,
    __hip_bfloat16* __restrict__ Opart, float* __restrict__ lpart, int lg)
{
    __shared__ __align__(16) __hip_bfloat16 sK[64][136];
    __shared__ __align__(16) __hip_bfloat16 sVt[128][72];
    __shared__ __align__(16) __hip_bfloat16 sP[8][16][72];

    const int s  = blockIdx.x;
    const int qt = 15 - blockIdx.y;
    const int b  = blockIdx.z;

    const int tid  = threadIdx.x;
    const int lane = tid & 63;
    const int w    = tid >> 6;
    const int quad = lane >> 4;
    const int l16  = lane & 15;

    const int t0 = qt * 128;
    const size_t brow = (size_t)b * T_;
    const __hip_bfloat16* vt_b = vtg + (size_t)b * HS_ * T_;

    const int nt = 2 * qt + 2;
    const int st_begin = (s * nt) >> lg;
    const int st_end   = ((s + 1) * nt) >> lg;

    bf16x8 aq[4];
    #pragma unroll
    for (int kt = 0; kt < 4; ++kt)
        aq[kt] = *(const bf16x8*)(qg + (brow + t0 + w * 16 + l16) * HS_ + kt * 32 + quad * 8);

    floatx4 acc_o[8];
    #pragma unroll
    for (int i = 0; i < 8; ++i) acc_o[i] = (floatx4){0.f, 0.f, 0.f, 0.f};
    float lsum[4] = {0.f, 0.f, 0.f, 0.f};

    const float scale = 0.08838834764831845f;

    const int kr0 = tid >> 4, ksg = tid & 15;
    const int vr0 = tid >> 3, vsg = tid & 7;

    bf16x8 pk[2], pv[2];
    if (st_begin < st_end) {
        const int s0 = st_begin * 64;
        pk[0] = *(const bf16x8*)(kg + (brow + s0 + kr0) * HS_ + ksg * 8);
        pk[1] = *(const bf16x8*)(kg + (brow + s0 + kr0 + 32) * HS_ + ksg * 8);
        pv[0] = *(const bf16x8*)(vt_b + (size_t)vr0 * T_ + s0 + vsg * 8);
        pv[1] = *(const bf16x8*)(vt_b + (size_t)(vr0 + 64) * T_ + s0 + vsg * 8);
    }

    for (int st = st_begin; st < st_end; ++st) {
        const int s0 = st * 64;
        __syncthreads();
        *(bf16x8*)&sK[kr0][ksg * 8]      = pk[0];
        *(bf16x8*)&sK[kr0 + 32][ksg * 8] = pk[1];
        *(bf16x8*)&sVt[vr0][vsg * 8]      = pv[0];
        *(bf16x8*)&sVt[vr0 + 64][vsg * 8] = pv[1];
        __syncthreads();

        if (st + 1 < st_end) {
            const int s1 = s0 + 64;
            pk[0] = *(const bf16x8*)(kg + (brow + s1 + kr0) * HS_ + ksg * 8);
            pk[1] = *(const bf16x8*)(kg + (brow + s1 + kr0 + 32) * HS_ + ksg * 8);
            pv[0] = *(const bf16x8*)(vt_b + (size_t)vr0 * T_ + s1 + vsg * 8);
            pv[1] = *(const bf16x8*)(vt_b + (size_t)(vr0 + 64) * T_ + s1 + vsg * 8);
        }

        floatx4 acc_s[4];
        #pragma unroll
        for (int c = 0; c < 4; ++c) acc_s[c] = (floatx4){0.f, 0.f, 0.f, 0.f};
        #pragma unroll
        for (int kt = 0; kt < 4; ++kt)
            #pragma unroll
            for (int c = 0; c < 4; ++c) {
                const bf16x8 bk = *(const bf16x8*)&sK[c * 16 + l16][kt * 32 + quad * 8];
                acc_s[c] = __builtin_amdgcn_mfma_f32_16x16x32_bf16(aq[kt], bk, acc_s[c], 0, 0, 0);
            }

        if (st >= nt - 2) {
            #pragma unroll
            for (int r = 0; r < 4; ++r) {
                const int grow = t0 + w * 16 + quad * 4 + r;
                #pragma unroll
                for (int c = 0; c < 4; ++c) {
                    const int gcol = s0 + c * 16 + l16;
                    float p = __expf(acc_s[c][r] * scale);
                    p = (gcol > grow) ? 0.f : p;
                    lsum[r] += p;
                    sP[w][quad * 4 + r][c * 16 + l16] = __float2bfloat16(p);
                }
            }
        } else {
            #pragma unroll
            for (int r = 0; r < 4; ++r)
                #pragma unroll
                for (int c = 0; c < 4; ++c) {
                    const float p = __expf(acc_s[c][r] * scale);
                    lsum[r] += p;
                    sP[w][quad * 4 + r][c * 16 + l16] = __float2bfloat16(p);
                }
        }

        #pragma unroll
        for (int ss = 0; ss < 2; ++ss) {
            const bf16x8 ap = *(const bf16x8*)&sP[w][l16][ss * 32 + quad * 8];
            #pragma unroll
            for (int c = 0; c < 8; ++c) {
                const bf16x8 bv = *(const bf16x8*)&sVt[c * 16 + l16][ss * 32 + quad * 8];
                acc_o[c] = __builtin_amdgcn_mfma_f32_16x16x32_bf16(ap, bv, acc_o[c], 0, 0, 0);
            }
        }
    }

    float lred[4];
    #pragma unroll
    for (int r = 0; r < 4; ++r) {
        float l = lsum[r];
        #pragma unroll
        for (int off = 8; off >= 1; off >>= 1) l += __shfl_xor(l, off, 64);
        lred[r] = l;
    }
    __hip_bfloat16* op = Opart + (size_t)s * M_ * HS_;
    #pragma unroll
    for (int c = 0; c < 8; ++c)
        #pragma unroll
        for (int r = 0; r < 4; ++r)
            op[(brow + t0 + w * 16 + quad * 4 + r) * HS_ + c * 16 + l16] =
                __float2bfloat16(acc_o[c][r]);
    if (l16 == 0) {
        #pragma unroll
        for (int r = 0; r < 4; ++r)
            lpart[s * M_ + brow + t0 + w * 16 + quad * 4 + r] = lred[r];
    }
}

// ---------------------------------------------------------------------------
// Merge nsplit key-split partials: out = (sum O_s) / (sum l_s).
// ---------------------------------------------------------------------------
__global__ void merge(const __hip_bfloat16* __restrict__ Opart,
                      const float* __restrict__ lpart, float* __restrict__ out,
                      int nsplit)
{
    const int idx = blockIdx.x * 256 + threadIdx.x;
    const int row = idx >> 4;
    const int c8  = (idx & 15) * 8;
    float l = 0.f;
    for (int sp = 0; sp < nsplit; ++sp) l += lpart[sp * M_ + row];
    const float inv = 1.0f / l;
    float o[8] = {0.f, 0.f, 0.f, 0.f, 0.f, 0.f, 0.f, 0.f};
    for (int sp = 0; sp < nsplit; ++sp) {
        const bf16x8 v = *(const bf16x8*)(Opart + (size_t)sp * M_ * HS_ + (size_t)row * HS_ + c8);
        #pragma unroll
        for (int j = 0; j < 8; ++j) o[j] += (float)v[j];
    }
    float4 ra, rb;
    ra.x = o[0] * inv; ra.y = o[1] * inv; ra.z = o[2] * inv; ra.w = o[3] * inv;
    rb.x = o[4] * inv; rb.y = o[5] * inv; rb.z = o[6] * inv; rb.w = o[7] * inv;
    *(float4*)(out + (size_t)row * HS_ + c8)     = ra;
    *(float4*)(out + (size_t)row * HS_ + c8 + 4) = rb;
}

extern "C" void kernel_launch(void* const* d_in, const int* in_sizes, int n_in,
                              void* d_out, int out_size, void* d_ws, size_t ws_size,
                              hipStream_t stream) {
    const float* x  = (const float*)d_in[0];
    const float* Wq = (const float*)d_in[1];
    const float* Wk = (const float*)d_in[2];
    const float* Wv = (const float*)d_in[3];
    char* ws = (char*)d_ws;

    // 8-way key split needs OFF_OP + 8*4MB (Opart) + 8*64KB (lpart) = 45.3 MB.
    const size_t need8 = (size_t)OFF_OP + 8u * 4194304u + 8u * 65536u;
    const int nsplit = (ws_size >= need8) ? 8 : 4;
    const int lg     = (nsplit == 8) ? 3 : 2;

    __hip_bfloat16* qg  = (__hip_bfloat16*)(ws + OFF_Q);
    __hip_bfloat16* kg  = (__hip_bfloat16*)(ws + OFF_K);
    __hip_bfloat16* vtg = (__hip_bfloat16*)(ws + OFF_VT);
    __hip_bfloat16* Wt  = (__hip_bfloat16*)(ws + OFF_WT);
    __hip_bfloat16* Opart = (__hip_bfloat16*)(ws + OFF_OP);
    float* lpart = (float*)(ws + OFF_OP + (size_t)nsplit * 4194304u);

    wprep<<<dim3(16, 3), 256, 0, stream>>>(Wq, Wk, Wv, Wt);
    qkv_gemm<<<dim3(256, 3), 256, 0, stream>>>(x, Wt, qg, kg, vtg);
    attn<<<dim3(nsplit, 16, 8), 512, 0, stream>>>(qg, kg, vtg, Opart, lpart, lg);
    merge<<<1024, 256, 0, stream>>>(Opart, lpart, (float*)d_out, nsplit);
}

// Round 7
// 173.160 us; speedup vs baseline: 1.0709x; 1.0709x over previous
//
#include <hip/hip_runtime.h>
#include <hip/hip_bf16.h>

// B=8, T=2048, D=1024, HS=128 causal attention head.
// wprep (W->Wt bf16) ; qkv_gemm (m97 async global_load_lds + XOR-swizzled LDS)
// attn (fixed-base softmax, 4-way split, 256-thr blocks, sP aliased in sK) ; merge.

typedef __bf16 bf16x8 __attribute__((ext_vector_type(8)));
typedef __bf16 bf16x4 __attribute__((ext_vector_type(4)));
typedef float floatx4 __attribute__((ext_vector_type(4)));

#define B_  8
#define T_  2048
#define D_  1024
#define HS_ 128
#define M_  (B_ * T_)   // 16384

// ws byte offsets (end = 30408704, proven safe)
#define OFF_Q   0u
#define OFF_K   4194304u
#define OFF_VT  8388608u
#define OFF_WT  12582912u          // 3*128*1024*2 = 786432
#define OFF_OP  13369344u          // 4 splits * 16384*128*2 (bf16) = 16777216
#define OFF_LP  30146560u          // 4 * 16384 * 4 = 262144

// async global->LDS, 16B/lane; dest = wave-uniform base + lane*16
#define GLL16(gp, lp) __builtin_amdgcn_global_load_lds( \
    (const __attribute__((address_space(1))) void*)(gp), \
    (__attribute__((address_space(3))) void*)(lp), 16, 0, 0)

// ---------------------------------------------------------------------------
// W[1024,128] fp32 -> Wt[128,1024] bf16 (x3), coalesced via LDS transpose.
// ---------------------------------------------------------------------------
__global__ __launch_bounds__(256) void wprep(
    const float* __restrict__ Wq, const float* __restrict__ Wk,
    const float* __restrict__ Wv, __hip_bfloat16* __restrict__ Wt)
{
    __shared__ __align__(16) __hip_bfloat16 sT[128][80];
    const int wsel = blockIdx.y;
    const int k0   = blockIdx.x * 64;
    const float* W = (wsel == 0) ? Wq : ((wsel == 1) ? Wk : Wv);

    #pragma unroll
    for (int i = 0; i < 8; ++i) {
        const int idx = threadIdx.x + i * 256;
        const int kr  = idx >> 5;
        const int f4  = idx & 31;
        const float4 v = *(const float4*)(W + (size_t)(k0 + kr) * HS_ + f4 * 4);
        sT[f4 * 4 + 0][kr] = __float2bfloat16(v.x);
        sT[f4 * 4 + 1][kr] = __float2bfloat16(v.y);
        sT[f4 * 4 + 2][kr] = __float2bfloat16(v.z);
        sT[f4 * 4 + 3][kr] = __float2bfloat16(v.w);
    }
    __syncthreads();
    #pragma unroll
    for (int i = 0; i < 4; ++i) {
        const int idx = threadIdx.x + i * 256;
        const int n   = idx >> 3;
        const int sg  = idx & 7;
        *(bf16x8*)(Wt + (size_t)wsel * HS_ * D_ + (size_t)n * D_ + k0 + sg * 8) =
            *(const bf16x8*)&sT[n][sg * 8];
    }
}

// ---------------------------------------------------------------------------
// QKV GEMM: C[16384,128] = bf16(x)*Wt^T. Tile 64x128, BK=64, grid (256,3).
// m97 structure: async global_load_lds into UNPADDED LDS, with an XOR swizzle
// applied on the SOURCE address so fragment reads are bank-spread:
//   sA(fp32)[r][chunk16B c'] holds global chunk c' ^ ((r&7)<<1)  (16 chunks/row)
//   sB(bf16)[n][chunk16B c'] holds global chunk c' ^ (n&7)        (8 chunks/row)
// Reads XOR the same mask (self-inverse). Masks are even so the A-fragment's
// two 16B chunks stay adjacent.
// ---------------------------------------------------------------------------
__global__ __launch_bounds__(256) void qkv_gemm(
    const float* __restrict__ x, const __hip_bfloat16* __restrict__ Wt_all,
    __hip_bfloat16* __restrict__ qg, __hip_bfloat16* __restrict__ kg,
    __hip_bfloat16* __restrict__ vtg)
{
    __shared__ __align__(16) float sAf[64][64];             // 16 KB
    __shared__ __align__(16) __hip_bfloat16 sBs[128][64];   // 16 KB

    const int mt   = blockIdx.x;
    const int wsel = blockIdx.y;
    const __hip_bfloat16* Wt = Wt_all + (size_t)wsel * HS_ * D_;

    const int tid  = threadIdx.x;
    const int lane = tid & 63;
    const int w    = tid >> 6;
    const int quad = lane >> 4;
    const int l16  = lane & 15;
    const int wrow = (w & 1) * 32;
    const int wcol = (w >> 1) * 64;
    const int m0   = mt * 64;

    // staging lane decomposition
    const int arL = lane >> 4, acL = lane & 15;   // A: 4 rows x 16 chunks per issue
    const int brL = lane >> 3, bcL = lane & 7;    // B: 8 rows x 8 chunks per issue

    floatx4 acc[2][4];
    #pragma unroll
    for (int i = 0; i < 2; ++i)
        #pragma unroll
        for (int j = 0; j < 4; ++j) acc[i][j] = (floatx4){0.f, 0.f, 0.f, 0.f};

    for (int kt = 0; kt < D_ / 64; ++kt) {
        const int k0 = kt * 64;
        #pragma unroll
        for (int i = 0; i < 4; ++i) {
            const int ar   = w * 16 + i * 4 + arL;          // sA row this lane fills
            const int swcA = acL ^ ((ar & 7) << 1);         // source 16B-chunk
            GLL16(x + (size_t)(m0 + ar) * D_ + k0 + swcA * 4, &sAf[w * 16 + i * 4][0]);
            const int br   = w * 32 + i * 8 + brL;          // sB row this lane fills
            const int swcB = bcL ^ (br & 7);
            GLL16(Wt + (size_t)br * D_ + k0 + swcB * 8, &sBs[w * 32 + i * 8][0]);
        }
        __syncthreads();   // drains vmcnt: async LDS writes visible

        #pragma unroll
        for (int ks = 0; ks < 2; ++ks) {
            bf16x8 af[2], bfr[4];
            #pragma unroll
            for (int i = 0; i < 2; ++i) {
                const int r   = wrow + i * 16 + l16;
                const int c0p = (ks * 8 + quad * 2) ^ ((r & 7) << 1);  // even mask
                const float4 f0 = *(const float4*)&sAf[r][c0p * 4];
                const float4 f1 = *(const float4*)&sAf[r][c0p * 4 + 4];
                union { bf16x8 v; __hip_bfloat16 h[8]; } u;
                u.h[0] = __float2bfloat16(f0.x); u.h[1] = __float2bfloat16(f0.y);
                u.h[2] = __float2bfloat16(f0.z); u.h[3] = __float2bfloat16(f0.w);
                u.h[4] = __float2bfloat16(f1.x); u.h[5] = __float2bfloat16(f1.y);
                u.h[6] = __float2bfloat16(f1.z); u.h[7] = __float2bfloat16(f1.w);
                af[i] = u.v;
            }
            #pragma unroll
            for (int j = 0; j < 4; ++j) {
                const int n  = wcol + j * 16 + l16;
                const int cp = (ks * 4 + quad) ^ (n & 7);
                bfr[j] = *(const bf16x8*)&sBs[n][cp * 8];
            }
            #pragma unroll
            for (int i = 0; i < 2; ++i)
                #pragma unroll
                for (int j = 0; j < 4; ++j)
                    acc[i][j] = __builtin_amdgcn_mfma_f32_16x16x32_bf16(af[i], bfr[j], acc[i][j], 0, 0, 0);
        }
        __syncthreads();   // all reads done before next tile's async writes
    }

    if (wsel < 2) {
        __hip_bfloat16* out = wsel ? kg : qg;
        #pragma unroll
        for (int i = 0; i < 2; ++i)
            #pragma unroll
            for (int j = 0; j < 4; ++j)
                #pragma unroll
                for (int r = 0; r < 4; ++r)
                    out[(size_t)(m0 + wrow + i * 16 + quad * 4 + r) * HS_ + wcol + j * 16 + l16] =
                        __float2bfloat16(acc[i][j][r]);
    } else {
        #pragma unroll
        for (int i = 0; i < 2; ++i) {
            const int row0 = m0 + wrow + i * 16 + quad * 4;
            const int bb = row0 >> 11;
            const int t  = row0 & 2047;
            #pragma unroll
            for (int j = 0; j < 4; ++j) {
                const int col = wcol + j * 16 + l16;
                union { bf16x4 v; __hip_bfloat16 h[4]; } u;
                #pragma unroll
                for (int r = 0; r < 4; ++r) u.h[r] = __float2bfloat16(acc[i][j][r]);
                *(bf16x4*)(vtg + (size_t)bb * HS_ * T_ + (size_t)col * T_ + t) = u.v;
            }
        }
    }
}

// ---------------------------------------------------------------------------
// Flash attention, fixed-base softmax. grid (4 split, 32 qt rev, 8 b),
// 256 threads = 4 waves, 64 q-rows/block. sP aliased into sK (extra barrier
// after QK^T) -> 35 KB LDS -> 4 blocks/CU. Register prefetch staging.
// ---------------------------------------------------------------------------
__global__ __launch_bounds__(256) void attn(
    const __hip_bfloat16* __restrict__ qg, const __hip_bfloat16* __restrict__ kg,
    const __hip_bfloat16* __restrict__ vtg,
    __hip_bfloat16* __restrict__ Opart, float* __restrict__ lpart)
{
    __shared__ __align__(16) __hip_bfloat16 sK[64][136];   // 17408 B; sP alias lives here
    __shared__ __align__(16) __hip_bfloat16 sVt[128][72];  // 18432 B
    __hip_bfloat16 (*sP)[72] = (__hip_bfloat16 (*)[72])&sK[0][0];  // [64][72] = 9216 B

    const int s  = blockIdx.x;
    const int qt = 31 - blockIdx.y;   // longest first
    const int b  = blockIdx.z;

    const int tid  = threadIdx.x;
    const int lane = tid & 63;
    const int w    = tid >> 6;        // 0..3
    const int quad = lane >> 4;
    const int l16  = lane & 15;

    const int t0 = qt * 64;
    const size_t brow = (size_t)b * T_;
    const __hip_bfloat16* vt_b = vtg + (size_t)b * HS_ * T_;

    const int nt = qt + 1;            // key tiles of 64
    const int st_begin = (s * nt) >> 2;
    const int st_end   = ((s + 1) * nt) >> 2;

    bf16x8 aq[4];
    #pragma unroll
    for (int kt = 0; kt < 4; ++kt)
        aq[kt] = *(const bf16x8*)(qg + (brow + t0 + w * 16 + l16) * HS_ + kt * 32 + quad * 8);

    floatx4 acc_o[8];
    #pragma unroll
    for (int i = 0; i < 8; ++i) acc_o[i] = (floatx4){0.f, 0.f, 0.f, 0.f};
    float lsum[4] = {0.f, 0.f, 0.f, 0.f};

    const float scale = 0.08838834764831845f;

    const int kr0 = tid >> 4, ksg = tid & 15;   // sK: 16 rows/issue-group x 16 segs
    const int vr0 = tid >> 3, vsg = tid & 7;    // sVt: 32 rows/issue-group x 8 segs

    bf16x8 pk[4], pv[4];
    if (st_begin < st_end) {
        const int s0 = st_begin * 64;
        #pragma unroll
        for (int i = 0; i < 4; ++i) {
            pk[i] = *(const bf16x8*)(kg + (brow + s0 + kr0 + i * 16) * HS_ + ksg * 8);
            pv[i] = *(const bf16x8*)(vt_b + (size_t)(vr0 + i * 32) * T_ + s0 + vsg * 8);
        }
    }

    for (int st = st_begin; st < st_end; ++st) {
        const int s0 = st * 64;
        __syncthreads();   // prior tile's sP/sVt reads complete
        #pragma unroll
        for (int i = 0; i < 4; ++i) {
            *(bf16x8*)&sK[kr0 + i * 16][ksg * 8] = pk[i];
            *(bf16x8*)&sVt[vr0 + i * 32][vsg * 8] = pv[i];
        }
        __syncthreads();

        if (st + 1 < st_end) {   // prefetch next tile; overlaps compute below
            const int s1 = s0 + 64;
            #pragma unroll
            for (int i = 0; i < 4; ++i) {
                pk[i] = *(const bf16x8*)(kg + (brow + s1 + kr0 + i * 16) * HS_ + ksg * 8);
                pv[i] = *(const bf16x8*)(vt_b + (size_t)(vr0 + i * 32) * T_ + s1 + vsg * 8);
            }
        }

        floatx4 acc_s[4];
        #pragma unroll
        for (int c = 0; c < 4; ++c) acc_s[c] = (floatx4){0.f, 0.f, 0.f, 0.f};
        #pragma unroll
        for (int kt = 0; kt < 4; ++kt)
            #pragma unroll
            for (int c = 0; c < 4; ++c) {
                const bf16x8 bk = *(const bf16x8*)&sK[c * 16 + l16][kt * 32 + quad * 8];
                acc_s[c] = __builtin_amdgcn_mfma_f32_16x16x32_bf16(aq[kt], bk, acc_s[c], 0, 0, 0);
            }
        __syncthreads();   // all waves done reading sK before sP overwrites it

        if (st == qt) {    // diagonal tile
            #pragma unroll
            for (int r = 0; r < 4; ++r) {
                const int grow = t0 + w * 16 + quad * 4 + r;
                #pragma unroll
                for (int c = 0; c < 4; ++c) {
                    const int gcol = s0 + c * 16 + l16;
                    float p = __expf(acc_s[c][r] * scale);
                    p = (gcol > grow) ? 0.f : p;
                    lsum[r] += p;
                    sP[w * 16 + quad * 4 + r][c * 16 + l16] = __float2bfloat16(p);
                }
            }
        } else {
            #pragma unroll
            for (int r = 0; r < 4; ++r)
                #pragma unroll
                for (int c = 0; c < 4; ++c) {
                    const float p = __expf(acc_s[c][r] * scale);
                    lsum[r] += p;
                    sP[w * 16 + quad * 4 + r][c * 16 + l16] = __float2bfloat16(p);
                }
        }
        // sP region is wave-private (rows w*16..w*16+15): no barrier before PV

        #pragma unroll
        for (int ss = 0; ss < 2; ++ss) {
            const bf16x8 ap = *(const bf16x8*)&sP[w * 16 + l16][ss * 32 + quad * 8];
            #pragma unroll
            for (int c = 0; c < 8; ++c) {
                const bf16x8 bv = *(const bf16x8*)&sVt[c * 16 + l16][ss * 32 + quad * 8];
                acc_o[c] = __builtin_amdgcn_mfma_f32_16x16x32_bf16(ap, bv, acc_o[c], 0, 0, 0);
            }
        }
    }

    float lred[4];
    #pragma unroll
    for (int r = 0; r < 4; ++r) {
        float l = lsum[r];
        #pragma unroll
        for (int off = 8; off >= 1; off >>= 1) l += __shfl_xor(l, off, 64);
        lred[r] = l;
    }
    __hip_bfloat16* op = Opart + (size_t)s * M_ * HS_;
    #pragma unroll
    for (int c = 0; c < 8; ++c)
        #pragma unroll
        for (int r = 0; r < 4; ++r)
            op[(brow + t0 + w * 16 + quad * 4 + r) * HS_ + c * 16 + l16] =
                __float2bfloat16(acc_o[c][r]);
    if (l16 == 0) {
        #pragma unroll
        for (int r = 0; r < 4; ++r)
            lpart[s * M_ + brow + t0 + w * 16 + quad * 4 + r] = lred[r];
    }
}

// ---------------------------------------------------------------------------
// Merge 4 key-split partials: out = (sum O_s) / (sum l_s).
// ---------------------------------------------------------------------------
__global__ void merge(const __hip_bfloat16* __restrict__ Opart,
                      const float* __restrict__ lpart, float* __restrict__ out)
{
    const int idx = blockIdx.x * 256 + threadIdx.x;
    const int row = idx >> 4;
    const int c8  = (idx & 15) * 8;
    const float l = lpart[row] + lpart[M_ + row] + lpart[2 * M_ + row] + lpart[3 * M_ + row];
    const float inv = 1.0f / l;
    float o[8] = {0.f, 0.f, 0.f, 0.f, 0.f, 0.f, 0.f, 0.f};
    #pragma unroll
    for (int sp = 0; sp < 4; ++sp) {
        const bf16x8 v = *(const bf16x8*)(Opart + (size_t)sp * M_ * HS_ + (size_t)row * HS_ + c8);
        #pragma unroll
        for (int j = 0; j < 8; ++j) o[j] += (float)v[j];
    }
    float4 ra, rb;
    ra.x = o[0] * inv; ra.y = o[1] * inv; ra.z = o[2] * inv; ra.w = o[3] * inv;
    rb.x = o[4] * inv; rb.y = o[5] * inv; rb.z = o[6] * inv; rb.w = o[7] * inv;
    *(float4*)(out + (size_t)row * HS_ + c8)     = ra;
    *(float4*)(out + (size_t)row * HS_ + c8 + 4) = rb;
}

extern "C" void kernel_launch(void* const* d_in, const int* in_sizes, int n_in,
                              void* d_out, int out_size, void* d_ws, size_t ws_size,
                              hipStream_t stream) {
    const float* x  = (const float*)d_in[0];
    const float* Wq = (const float*)d_in[1];
    const float* Wk = (const float*)d_in[2];
    const float* Wv = (const float*)d_in[3];
    char* ws = (char*)d_ws;

    __hip_bfloat16* qg  = (__hip_bfloat16*)(ws + OFF_Q);
    __hip_bfloat16* kg  = (__hip_bfloat16*)(ws + OFF_K);
    __hip_bfloat16* vtg = (__hip_bfloat16*)(ws + OFF_VT);
    __hip_bfloat16* Wt  = (__hip_bfloat16*)(ws + OFF_WT);
    __hip_bfloat16* Opart = (__hip_bfloat16*)(ws + OFF_OP);
    float* lpart = (float*)(ws + OFF_LP);

    wprep<<<dim3(16, 3), 256, 0, stream>>>(Wq, Wk, Wv, Wt);
    qkv_gemm<<<dim3(256, 3), 256, 0, stream>>>(x, Wt, qg, kg, vtg);
    attn<<<dim3(4, 32, 8), 256, 0, stream>>>(qg, kg, vtg, Opart, lpart);
    merge<<<1024, 256, 0, stream>>>(Opart, lpart, (float*)d_out);
}

// Round 8
// 155.813 us; speedup vs baseline: 1.1902x; 1.1113x over previous
//
#include <hip/hip_runtime.h>
#include <hip/hip_bf16.h>

// B=8, T=2048, D=1024, HS=128 causal attention head.
// wprep (W->Wt bf16) ; qkv_gemm (async global_load_lds + FULL-mask XOR swizzle)
// attn (fixed-base softmax, 4-way split, 256-thr blocks, sP aliased in sK) ; merge.

typedef __bf16 bf16x8 __attribute__((ext_vector_type(8)));
typedef __bf16 bf16x4 __attribute__((ext_vector_type(4)));
typedef float floatx4 __attribute__((ext_vector_type(4)));

#define B_  8
#define T_  2048
#define D_  1024
#define HS_ 128
#define M_  (B_ * T_)   // 16384

// ws byte offsets (end = 30408704, proven safe)
#define OFF_Q   0u
#define OFF_K   4194304u
#define OFF_VT  8388608u
#define OFF_WT  12582912u          // 3*128*1024*2 = 786432
#define OFF_OP  13369344u          // 4 splits * 16384*128*2 (bf16) = 16777216
#define OFF_LP  30146560u          // 4 * 16384 * 4 = 262144

// async global->LDS, 16B/lane; dest = wave-uniform base + lane*16
#define GLL16(gp, lp) __builtin_amdgcn_global_load_lds( \
    (const __attribute__((address_space(1))) void*)(gp), \
    (__attribute__((address_space(3))) void*)(lp), 16, 0, 0)

// ---------------------------------------------------------------------------
// W[1024,128] fp32 -> Wt[128,1024] bf16 (x3), coalesced via LDS transpose.
// ---------------------------------------------------------------------------
__global__ __launch_bounds__(256) void wprep(
    const float* __restrict__ Wq, const float* __restrict__ Wk,
    const float* __restrict__ Wv, __hip_bfloat16* __restrict__ Wt)
{
    __shared__ __align__(16) __hip_bfloat16 sT[128][80];
    const int wsel = blockIdx.y;
    const int k0   = blockIdx.x * 64;
    const float* W = (wsel == 0) ? Wq : ((wsel == 1) ? Wk : Wv);

    #pragma unroll
    for (int i = 0; i < 8; ++i) {
        const int idx = threadIdx.x + i * 256;
        const int kr  = idx >> 5;
        const int f4  = idx & 31;
        const float4 v = *(const float4*)(W + (size_t)(k0 + kr) * HS_ + f4 * 4);
        sT[f4 * 4 + 0][kr] = __float2bfloat16(v.x);
        sT[f4 * 4 + 1][kr] = __float2bfloat16(v.y);
        sT[f4 * 4 + 2][kr] = __float2bfloat16(v.z);
        sT[f4 * 4 + 3][kr] = __float2bfloat16(v.w);
    }
    __syncthreads();
    #pragma unroll
    for (int i = 0; i < 4; ++i) {
        const int idx = threadIdx.x + i * 256;
        const int n   = idx >> 3;
        const int sg  = idx & 7;
        *(bf16x8*)(Wt + (size_t)wsel * HS_ * D_ + (size_t)n * D_ + k0 + sg * 8) =
            *(const bf16x8*)&sT[n][sg * 8];
    }
}

// ---------------------------------------------------------------------------
// QKV GEMM: C[16384,128] = bf16(x)*Wt^T. Tile 64x128, BK=64, grid (256,3).
// Async global_load_lds into UNPADDED LDS with a SOURCE-side XOR swizzle:
//   sA(fp32)[r][16B chunk c'] holds global chunk c' ^ (r&15)   (16 chunks/row)
//   sB(bf16)[n][16B chunk c'] holds global chunk c' ^ (n&7)    (8 chunks/row)
// Reads XOR the same mask (self-inverse). Full-width masks -> per 16-lane
// phase every bank-start pair is hit by exactly 2 lanes (2-way = free, m136).
// ---------------------------------------------------------------------------
__global__ __launch_bounds__(256) void qkv_gemm(
    const float* __restrict__ x, const __hip_bfloat16* __restrict__ Wt_all,
    __hip_bfloat16* __restrict__ qg, __hip_bfloat16* __restrict__ kg,
    __hip_bfloat16* __restrict__ vtg)
{
    __shared__ __align__(16) float sAf[64][64];             // 16 KB
    __shared__ __align__(16) __hip_bfloat16 sBs[128][64];   // 16 KB

    const int mt   = blockIdx.x;
    const int wsel = blockIdx.y;
    const __hip_bfloat16* Wt = Wt_all + (size_t)wsel * HS_ * D_;

    const int tid  = threadIdx.x;
    const int lane = tid & 63;
    const int w    = tid >> 6;
    const int quad = lane >> 4;
    const int l16  = lane & 15;
    const int wrow = (w & 1) * 32;
    const int wcol = (w >> 1) * 64;
    const int m0   = mt * 64;

    // staging lane decomposition
    const int arL = lane >> 4, acL = lane & 15;   // A: 4 rows x 16 chunks per issue
    const int brL = lane >> 3, bcL = lane & 7;    // B: 8 rows x 8 chunks per issue

    floatx4 acc[2][4];
    #pragma unroll
    for (int i = 0; i < 2; ++i)
        #pragma unroll
        for (int j = 0; j < 4; ++j) acc[i][j] = (floatx4){0.f, 0.f, 0.f, 0.f};

    for (int kt = 0; kt < D_ / 64; ++kt) {
        const int k0 = kt * 64;
        #pragma unroll
        for (int i = 0; i < 4; ++i) {
            const int arow = i * 4 + arL;                   // row within the 16-row group
            const int swcA = acL ^ arow;                    // full 4-bit mask
            GLL16(x + (size_t)(m0 + w * 16 + arow) * D_ + k0 + swcA * 4,
                  &sAf[w * 16 + i * 4][0]);
            const int brow = i * 8 + brL;                   // row within the 32-row group
            const int swcB = bcL ^ (brow & 7);              // full 3-bit mask
            GLL16(Wt + (size_t)(w * 32 + brow) * D_ + k0 + swcB * 8,
                  &sBs[w * 32 + i * 8][0]);
        }
        __syncthreads();   // drains vmcnt: async LDS writes visible

        #pragma unroll
        for (int ks = 0; ks < 2; ++ks) {
            bf16x8 af[2], bfr[4];
            #pragma unroll
            for (int i = 0; i < 2; ++i) {
                const int r  = wrow + i * 16 + l16;         // r & 15 == l16
                const int g0 = (ks * 8 + quad * 2) ^ l16;   // LDS chunk of global g
                const int g1 = (ks * 8 + quad * 2 + 1) ^ l16;
                const float4 f0 = *(const float4*)&sAf[r][g0 * 4];
                const float4 f1 = *(const float4*)&sAf[r][g1 * 4];
                union { bf16x8 v; __hip_bfloat16 h[8]; } u;
                u.h[0] = __float2bfloat16(f0.x); u.h[1] = __float2bfloat16(f0.y);
                u.h[2] = __float2bfloat16(f0.z); u.h[3] = __float2bfloat16(f0.w);
                u.h[4] = __float2bfloat16(f1.x); u.h[5] = __float2bfloat16(f1.y);
                u.h[6] = __float2bfloat16(f1.z); u.h[7] = __float2bfloat16(f1.w);
                af[i] = u.v;
            }
            #pragma unroll
            for (int j = 0; j < 4; ++j) {
                const int n  = wcol + j * 16 + l16;
                const int cp = (ks * 4 + quad) ^ (n & 7);
                bfr[j] = *(const bf16x8*)&sBs[n][cp * 8];
            }
            #pragma unroll
            for (int i = 0; i < 2; ++i)
                #pragma unroll
                for (int j = 0; j < 4; ++j)
                    acc[i][j] = __builtin_amdgcn_mfma_f32_16x16x32_bf16(af[i], bfr[j], acc[i][j], 0, 0, 0);
        }
        __syncthreads();   // all reads done before next tile's async writes
    }

    if (wsel < 2) {
        __hip_bfloat16* out = wsel ? kg : qg;
        #pragma unroll
        for (int i = 0; i < 2; ++i)
            #pragma unroll
            for (int j = 0; j < 4; ++j)
                #pragma unroll
                for (int r = 0; r < 4; ++r)
                    out[(size_t)(m0 + wrow + i * 16 + quad * 4 + r) * HS_ + wcol + j * 16 + l16] =
                        __float2bfloat16(acc[i][j][r]);
    } else {
        #pragma unroll
        for (int i = 0; i < 2; ++i) {
            const int row0 = m0 + wrow + i * 16 + quad * 4;
            const int bb = row0 >> 11;
            const int t  = row0 & 2047;
            #pragma unroll
            for (int j = 0; j < 4; ++j) {
                const int col = wcol + j * 16 + l16;
                union { bf16x4 v; __hip_bfloat16 h[4]; } u;
                #pragma unroll
                for (int r = 0; r < 4; ++r) u.h[r] = __float2bfloat16(acc[i][j][r]);
                *(bf16x4*)(vtg + (size_t)bb * HS_ * T_ + (size_t)col * T_ + t) = u.v;
            }
        }
    }
}

// ---------------------------------------------------------------------------
// Flash attention, fixed-base softmax. grid (4 split, 32 qt rev, 8 b),
// 256 threads = 4 waves, 64 q-rows/block. sP aliased into sK (extra barrier
// after QK^T) -> 35 KB LDS -> 4 blocks/CU. Register prefetch staging.
// ---------------------------------------------------------------------------
__global__ __launch_bounds__(256) void attn(
    const __hip_bfloat16* __restrict__ qg, const __hip_bfloat16* __restrict__ kg,
    const __hip_bfloat16* __restrict__ vtg,
    __hip_bfloat16* __restrict__ Opart, float* __restrict__ lpart)
{
    __shared__ __align__(16) __hip_bfloat16 sK[64][136];   // 17408 B; sP alias lives here
    __shared__ __align__(16) __hip_bfloat16 sVt[128][72];  // 18432 B
    __hip_bfloat16 (*sP)[72] = (__hip_bfloat16 (*)[72])&sK[0][0];  // [64][72]

    const int s  = blockIdx.x;
    const int qt = 31 - blockIdx.y;   // longest first
    const int b  = blockIdx.z;

    const int tid  = threadIdx.x;
    const int lane = tid & 63;
    const int w    = tid >> 6;        // 0..3
    const int quad = lane >> 4;
    const int l16  = lane & 15;

    const int t0 = qt * 64;
    const size_t brow = (size_t)b * T_;
    const __hip_bfloat16* vt_b = vtg + (size_t)b * HS_ * T_;

    const int nt = qt + 1;            // key tiles of 64
    const int st_begin = (s * nt) >> 2;
    const int st_end   = ((s + 1) * nt) >> 2;

    bf16x8 aq[4];
    #pragma unroll
    for (int kt = 0; kt < 4; ++kt)
        aq[kt] = *(const bf16x8*)(qg + (brow + t0 + w * 16 + l16) * HS_ + kt * 32 + quad * 8);

    floatx4 acc_o[8];
    #pragma unroll
    for (int i = 0; i < 8; ++i) acc_o[i] = (floatx4){0.f, 0.f, 0.f, 0.f};
    float lsum[4] = {0.f, 0.f, 0.f, 0.f};

    const float scale = 0.08838834764831845f;

    const int kr0 = tid >> 4, ksg = tid & 15;
    const int vr0 = tid >> 3, vsg = tid & 7;

    bf16x8 pk[4], pv[4];
    if (st_begin < st_end) {
        const int s0 = st_begin * 64;
        #pragma unroll
        for (int i = 0; i < 4; ++i) {
            pk[i] = *(const bf16x8*)(kg + (brow + s0 + kr0 + i * 16) * HS_ + ksg * 8);
            pv[i] = *(const bf16x8*)(vt_b + (size_t)(vr0 + i * 32) * T_ + s0 + vsg * 8);
        }
    }

    for (int st = st_begin; st < st_end; ++st) {
        const int s0 = st * 64;
        __syncthreads();   // prior tile's sP/sVt reads complete
        #pragma unroll
        for (int i = 0; i < 4; ++i) {
            *(bf16x8*)&sK[kr0 + i * 16][ksg * 8] = pk[i];
            *(bf16x8*)&sVt[vr0 + i * 32][vsg * 8] = pv[i];
        }
        __syncthreads();

        if (st + 1 < st_end) {   // prefetch next tile; overlaps compute below
            const int s1 = s0 + 64;
            #pragma unroll
            for (int i = 0; i < 4; ++i) {
                pk[i] = *(const bf16x8*)(kg + (brow + s1 + kr0 + i * 16) * HS_ + ksg * 8);
                pv[i] = *(const bf16x8*)(vt_b + (size_t)(vr0 + i * 32) * T_ + s1 + vsg * 8);
            }
        }

        floatx4 acc_s[4];
        #pragma unroll
        for (int c = 0; c < 4; ++c) acc_s[c] = (floatx4){0.f, 0.f, 0.f, 0.f};
        #pragma unroll
        for (int kt = 0; kt < 4; ++kt)
            #pragma unroll
            for (int c = 0; c < 4; ++c) {
                const bf16x8 bk = *(const bf16x8*)&sK[c * 16 + l16][kt * 32 + quad * 8];
                acc_s[c] = __builtin_amdgcn_mfma_f32_16x16x32_bf16(aq[kt], bk, acc_s[c], 0, 0, 0);
            }
        __syncthreads();   // all waves done reading sK before sP overwrites it

        if (st == qt) {    // diagonal tile
            #pragma unroll
            for (int r = 0; r < 4; ++r) {
                const int grow = t0 + w * 16 + quad * 4 + r;
                #pragma unroll
                for (int c = 0; c < 4; ++c) {
                    const int gcol = s0 + c * 16 + l16;
                    float p = __expf(acc_s[c][r] * scale);
                    p = (gcol > grow) ? 0.f : p;
                    lsum[r] += p;
                    sP[w * 16 + quad * 4 + r][c * 16 + l16] = __float2bfloat16(p);
                }
            }
        } else {
            #pragma unroll
            for (int r = 0; r < 4; ++r)
                #pragma unroll
                for (int c = 0; c < 4; ++c) {
                    const float p = __expf(acc_s[c][r] * scale);
                    lsum[r] += p;
                    sP[w * 16 + quad * 4 + r][c * 16 + l16] = __float2bfloat16(p);
                }
        }
        // sP region is wave-private (rows w*16..w*16+15): no barrier before PV

        #pragma unroll
        for (int ss = 0; ss < 2; ++ss) {
            const bf16x8 ap = *(const bf16x8*)&sP[w * 16 + l16][ss * 32 + quad * 8];
            #pragma unroll
            for (int c = 0; c < 8; ++c) {
                const bf16x8 bv = *(const bf16x8*)&sVt[c * 16 + l16][ss * 32 + quad * 8];
                acc_o[c] = __builtin_amdgcn_mfma_f32_16x16x32_bf16(ap, bv, acc_o[c], 0, 0, 0);
            }
        }
    }

    float lred[4];
    #pragma unroll
    for (int r = 0; r < 4; ++r) {
        float l = lsum[r];
        #pragma unroll
        for (int off = 8; off >= 1; off >>= 1) l += __shfl_xor(l, off, 64);
        lred[r] = l;
    }
    __hip_bfloat16* op = Opart + (size_t)s * M_ * HS_;
    #pragma unroll
    for (int c = 0; c < 8; ++c)
        #pragma unroll
        for (int r = 0; r < 4; ++r)
            op[(brow + t0 + w * 16 + quad * 4 + r) * HS_ + c * 16 + l16] =
                __float2bfloat16(acc_o[c][r]);
    if (l16 == 0) {
        #pragma unroll
        for (int r = 0; r < 4; ++r)
            lpart[s * M_ + brow + t0 + w * 16 + quad * 4 + r] = lred[r];
    }
}

// ---------------------------------------------------------------------------
// Merge 4 key-split partials: out = (sum O_s) / (sum l_s).
// ---------------------------------------------------------------------------
__global__ void merge(const __hip_bfloat16* __restrict__ Opart,
                      const float* __restrict__ lpart, float* __restrict__ out)
{
    const int idx = blockIdx.x * 256 + threadIdx.x;
    const int row = idx >> 4;
    const int c8  = (idx & 15) * 8;
    const float l = lpart[row] + lpart[M_ + row] + lpart[2 * M_ + row] + lpart[3 * M_ + row];
    const float inv = 1.0f / l;
    float o[8] = {0.f, 0.f, 0.f, 0.f, 0.f, 0.f, 0.f, 0.f};
    #pragma unroll
    for (int sp = 0; sp < 4; ++sp) {
        const bf16x8 v = *(const bf16x8*)(Opart + (size_t)sp * M_ * HS_ + (size_t)row * HS_ + c8);
        #pragma unroll
        for (int j = 0; j < 8; ++j) o[j] += (float)v[j];
    }
    float4 ra, rb;
    ra.x = o[0] * inv; ra.y = o[1] * inv; ra.z = o[2] * inv; ra.w = o[3] * inv;
    rb.x = o[4] * inv; rb.y = o[5] * inv; rb.z = o[6] * inv; rb.w = o[7] * inv;
    *(float4*)(out + (size_t)row * HS_ + c8)     = ra;
    *(float4*)(out + (size_t)row * HS_ + c8 + 4) = rb;
}

extern "C" void kernel_launch(void* const* d_in, const int* in_sizes, int n_in,
                              void* d_out, int out_size, void* d_ws, size_t ws_size,
                              hipStream_t stream) {
    const float* x  = (const float*)d_in[0];
    const float* Wq = (const float*)d_in[1];
    const float* Wk = (const float*)d_in[2];
    const float* Wv = (const float*)d_in[3];
    char* ws = (char*)d_ws;

    __hip_bfloat16* qg  = (__hip_bfloat16*)(ws + OFF_Q);
    __hip_bfloat16* kg  = (__hip_bfloat16*)(ws + OFF_K);
    __hip_bfloat16* vtg = (__hip_bfloat16*)(ws + OFF_VT);
    __hip_bfloat16* Wt  = (__hip_bfloat16*)(ws + OFF_WT);
    __hip_bfloat16* Opart = (__hip_bfloat16*)(ws + OFF_OP);
    float* lpart = (float*)(ws + OFF_LP);

    wprep<<<dim3(16, 3), 256, 0, stream>>>(Wq, Wk, Wv, Wt);
    qkv_gemm<<<dim3(256, 3), 256, 0, stream>>>(x, Wt, qg, kg, vtg);
    attn<<<dim3(4, 32, 8), 256, 0, stream>>>(qg, kg, vtg, Opart, lpart);
    merge<<<1024, 256, 0, stream>>>(Opart, lpart, (float*)d_out);
}